// Round 5
// baseline (629.460 us; speedup 1.0000x reference)
//
#include <hip/hip_runtime.h>
#include <math.h>

#define N_NODES 20000
#define N_EDGES 640000
#define ETOT (N_EDGES + N_NODES)
#define HC 256
#define NLAYER 3
#define NBATCH 16
#define GEPS 1e-5f
#define NSLOT 64

typedef unsigned short u16;
typedef unsigned int u32;
typedef __attribute__((ext_vector_type(8))) short short8;
typedef __attribute__((ext_vector_type(4))) float floatx4;

__device__ __forceinline__ u16 f2bf(float f) {
    u32 u = __float_as_uint(f);
    u32 r = (u + 0x7FFFu + ((u >> 16) & 1u)) >> 16;
    return (u16)r;
}

__device__ __forceinline__ float4 bf2f4(uint2 u) {
    float4 r;
    r.x = __uint_as_float(u.x << 16);
    r.y = __uint_as_float(u.x & 0xFFFF0000u);
    r.z = __uint_as_float(u.y << 16);
    r.w = __uint_as_float(u.y & 0xFFFF0000u);
    return r;
}

// VALU-only 16-lane butterfly sum
__device__ __forceinline__ float dpp_red16(float x) {
    x += __int_as_float(__builtin_amdgcn_update_dpp(0, __float_as_int(x), 0xB1, 0xF, 0xF, true));
    x += __int_as_float(__builtin_amdgcn_update_dpp(0, __float_as_int(x), 0x4E, 0xF, 0xF, true));
    x += __int_as_float(__builtin_amdgcn_update_dpp(0, __float_as_int(x), 0x141, 0xF, 0xF, true));
    x += __int_as_float(__builtin_amdgcn_update_dpp(0, __float_as_int(x), 0x140, 0xF, 0xF, true));
    return x;
}

// ---------------- prep: convert x to bf16, transpose W, zero scratch ----------------
// grid: [0,1000) convert, [1000,1384) transpose, [1384,1504) zero

__global__ __launch_bounds__(256) void prep(const float* __restrict__ x, u16* __restrict__ xbf,
                                            const float* __restrict__ Wl, const float* __restrict__ Wr,
                                            u16* __restrict__ WT, uint4* __restrict__ zbase, int zq) {
    int b = blockIdx.x, tid = threadIdx.x;
    if (b < 1000) {
        for (int i = b * 256 + tid; i < 640000; i += 256000) {
            const float4* x4 = (const float4*)x + (size_t)i * 2;
            float4 a = x4[0], c = x4[1];
            u16 o[8] = {f2bf(a.x), f2bf(a.y), f2bf(a.z), f2bf(a.w),
                        f2bf(c.x), f2bf(c.y), f2bf(c.z), f2bf(c.w)};
            ((uint4*)xbf)[i] = *(const uint4*)o;
        }
    } else if (b < 1384) {
        __shared__ float T[32][33];
        int bi = b - 1000;
        int kb = bi & 7, nbk = (bi >> 3) & 15, l = bi >> 7;
        int n0 = nbk * 32, k0 = kb * 32;
        const float* W = ((n0 < 256) ? Wl : Wr) + (size_t)l * 65536;
        int nn = n0 & 255;
        int tx = tid & 31, ty = tid >> 5;
        #pragma unroll
        for (int i = 0; i < 4; ++i)
            T[ty + i * 8][tx] = W[(size_t)(k0 + ty + i * 8) * 256 + nn + tx];
        __syncthreads();
        u16* outw = WT + (size_t)l * 512 * 256;
        #pragma unroll
        for (int i = 0; i < 4; ++i)
            outw[(size_t)(n0 + ty + i * 8) * 256 + k0 + tx] = f2bf(T[tx][ty + i * 8]);
    } else {
        uint4 z = make_uint4(0, 0, 0, 0);
        for (int i = (b - 1384) * 256 + tid; i < zq; i += 120 * 256) zbase[i] = z;
    }
}

// ---------------- fused CSR build with grid barrier ----------------
// 256 blocks x 256 threads (1024 waves << 8192-wave capacity -> co-resident)

__device__ __forceinline__ void gbar(int* bar, int target) {
    __syncthreads();
    if (threadIdx.x == 0) {
        __threadfence();
        atomicAdd(bar, 1);
        while (atomicAdd(bar, 0) < target) __builtin_amdgcn_s_sleep(8);
        __threadfence();
    }
    __syncthreads();
}

__global__ __launch_bounds__(256) void csr_fused(const int* __restrict__ src, const int* __restrict__ dst,
                                                 int* __restrict__ rowptr, int* __restrict__ cursor,
                                                 int* __restrict__ colx, int* bar,
                                                 int* __restrict__ blocksum) {
    int tid = threadIdx.x, b = blockIdx.x;
    int gid = b * 256 + tid;
    __shared__ int sdata[256];
    __shared__ int loc[80];

    // phase B: degree count (rowptr pre-zeroed by prep)
    for (int e = gid; e < N_EDGES; e += 65536) atomicAdd(&rowptr[dst[e]], 1);
    gbar(bar, 256);

    // phase C: block sums (incl. +1 self-loop)
    int n0 = b * 79, n1 = min(n0 + 79, N_NODES);
    if (n0 > N_NODES) n1 = n0;
    int v = 0;
    if (n0 + tid < n1) { v = rowptr[n0 + tid] + 1; loc[tid] = v; }
    sdata[tid] = v;
    __syncthreads();
    for (int s2 = 128; s2 > 0; s2 >>= 1) {
        if (tid < s2) sdata[tid] += sdata[tid + s2];
        __syncthreads();
    }
    if (tid == 0) blocksum[b] = sdata[0];
    gbar(bar, 512);

    // phase D: block 0 exclusive scan of 256 block sums
    if (b == 0) {
        int mine = blocksum[tid];
        sdata[tid] = mine;
        __syncthreads();
        for (int off2 = 1; off2 < 256; off2 <<= 1) {
            int t2 = (tid >= off2) ? sdata[tid - off2] : 0;
            __syncthreads();
            sdata[tid] += t2;
            __syncthreads();
        }
        blocksum[tid] = sdata[tid] - mine;  // exclusive
    }
    gbar(bar, 768);

    // phase E: local exclusive scan -> rowptr/cursor
    if (tid == 0) {
        int run = blocksum[b];
        for (int i = n0; i < n1; ++i) {
            int d = loc[i - n0];
            rowptr[i] = run;
            cursor[i] = run;
            run += d;
        }
        if (b == 255) rowptr[N_NODES] = ETOT;
    }
    gbar(bar, 1024);

    // phase F: scatter (self-loops + edges)
    for (int t = gid; t < ETOT; t += 65536) {
        if (t < N_NODES) {
            int p = atomicAdd(&cursor[t], 1);
            colx[p] = t;
        } else {
            int e = t - N_NODES;
            int p = atomicAdd(&cursor[dst[e]], 1);
            colx[p] = src[e];
        }
    }
}

// ---------------- bf16 MFMA dual GEMM with fused GraphNorm+PReLU on A ----------------
// A: bf16 [20000][256] (xbf for layer 0, hB for layers 1-2); norm applied in staging.

__global__ __launch_bounds__(256) void gemm_mfma(
    const u16* __restrict__ Asrc, const float* __restrict__ slots_prev,
    const float* __restrict__ nw, const float* __restrict__ nb, const float* __restrict__ na,
    const float* __restrict__ pa, int prelu_idx, int use_norm,
    const u16* __restrict__ WT,
    const float* __restrict__ b0, const float* __restrict__ b1,
    u16* __restrict__ xlb, float* __restrict__ xrf) {
    __shared__ u16 As[128][40];
    __shared__ u16 Bs[128][40];
    __shared__ float wcL[256], bbL[256];
    int row0 = blockIdx.x * 128;
    int nstrip = blockIdx.y;                 // 0,1 -> xl bf16; 2,3 -> xr fp32
    int ncol0 = nstrip * 128;
    const float* bias = (nstrip < 2) ? b0 : b1;

    int tid = threadIdx.x;
    float ap = 0.f;
    if (use_norm) {
        int c = tid;
        float sum = 0.f, sq = 0.f;
        for (int s = 0; s < NSLOT; ++s) {
            sum += slots_prev[s * 512 + c];
            sq += slots_prev[s * 512 + 256 + c];
        }
        const float invn = 1.f / (float)N_NODES;
        float mean = sum * invn, Eh2 = sq * invn;
        float a = na[c];
        float var = Eh2 - (2.f * a - a * a) * mean * mean;
        float wc = nw[c] * rsqrtf(var + GEPS);
        wcL[c] = wc;
        bbL[c] = nb[c] - a * mean * wc;
        ap = pa[prelu_idx];
        __syncthreads();
    }

    int wave = tid >> 6, lane = tid & 63;
    int wm = (wave & 1) * 64, wn = (wave >> 1) * 64;
    int quad = lane >> 4, l16 = lane & 15;

    floatx4 acc[4][4] = {};

    int sr = tid >> 1;
    int sh = (tid & 1) * 16;

    for (int k0 = 0; k0 < 256; k0 += 32) {
        int gr = row0 + sr;
        uint4 av0 = make_uint4(0, 0, 0, 0), av1 = make_uint4(0, 0, 0, 0);
        if (gr < N_NODES) {
            const u16* p = Asrc + (size_t)gr * 256 + k0 + sh;
            av0 = *(const uint4*)p;
            av1 = *(const uint4*)(p + 8);
        }
        if (use_norm) {
            int kb2 = k0 + sh;
            u16 tmp[16];
            *(uint4*)tmp = av0;
            *(uint4*)(tmp + 8) = av1;
            float4 wv0 = *(const float4*)&wcL[kb2], wv1 = *(const float4*)&wcL[kb2 + 4];
            float4 wv2 = *(const float4*)&wcL[kb2 + 8], wv3 = *(const float4*)&wcL[kb2 + 12];
            float4 bv0 = *(const float4*)&bbL[kb2], bv1 = *(const float4*)&bbL[kb2 + 4];
            float4 bv2 = *(const float4*)&bbL[kb2 + 8], bv3 = *(const float4*)&bbL[kb2 + 12];
            float wvf[16] = {wv0.x, wv0.y, wv0.z, wv0.w, wv1.x, wv1.y, wv1.z, wv1.w,
                             wv2.x, wv2.y, wv2.z, wv2.w, wv3.x, wv3.y, wv3.z, wv3.w};
            float bvf[16] = {bv0.x, bv0.y, bv0.z, bv0.w, bv1.x, bv1.y, bv1.z, bv1.w,
                             bv2.x, bv2.y, bv2.z, bv2.w, bv3.x, bv3.y, bv3.z, bv3.w};
            u16 outv[16];
            #pragma unroll
            for (int j = 0; j < 16; ++j) {
                float vv = __uint_as_float(((u32)tmp[j]) << 16);
                float t2 = vv * wvf[j] + bvf[j];
                t2 = fmaxf(t2, ap * t2);
                outv[j] = f2bf(t2);
            }
            av0 = *(const uint4*)outv;
            av1 = *(const uint4*)(outv + 8);
        }
        const u16* q = WT + (size_t)(ncol0 + sr) * 256 + k0 + sh;
        uint4 bw0 = *(const uint4*)q;
        uint4 bw1 = *(const uint4*)(q + 8);
        *(uint4*)&As[sr][sh] = av0;
        *(uint4*)&As[sr][sh + 8] = av1;
        *(uint4*)&Bs[sr][sh] = bw0;
        *(uint4*)&Bs[sr][sh + 8] = bw1;
        __syncthreads();

        short8 af[4], bfr[4];
        #pragma unroll
        for (int mi = 0; mi < 4; ++mi)
            af[mi] = *(const short8*)&As[wm + mi * 16 + l16][quad * 8];
        #pragma unroll
        for (int ni = 0; ni < 4; ++ni)
            bfr[ni] = *(const short8*)&Bs[wn + ni * 16 + l16][quad * 8];
        #pragma unroll
        for (int mi = 0; mi < 4; ++mi)
            #pragma unroll
            for (int ni = 0; ni < 4; ++ni)
                acc[mi][ni] = __builtin_amdgcn_mfma_f32_16x16x32_bf16(af[mi], bfr[ni], acc[mi][ni], 0, 0, 0);
        __syncthreads();
    }

    // C/D layout: col = lane&15, row = quad*4 + reg
    if (nstrip < 2) {
        int c0 = nstrip * 128;
        #pragma unroll
        for (int ni = 0; ni < 4; ++ni) {
            int col = c0 + wn + ni * 16 + l16;
            float bv = bias[col];
            #pragma unroll
            for (int mi = 0; mi < 4; ++mi) {
                int gr = row0 + wm + mi * 16 + quad * 4;
                #pragma unroll
                for (int r = 0; r < 4; ++r) {
                    if (gr + r < N_NODES)
                        xlb[(size_t)(gr + r) * 256 + col] = f2bf(acc[mi][ni][r] + bv);
                }
            }
        }
    } else {
        int c0 = (nstrip - 2) * 128;
        #pragma unroll
        for (int ni = 0; ni < 4; ++ni) {
            int col = c0 + wn + ni * 16 + l16;
            float bv = bias[col];
            #pragma unroll
            for (int mi = 0; mi < 4; ++mi) {
                int gr = row0 + wm + mi * 16 + quad * 4;
                #pragma unroll
                for (int r = 0; r < 4; ++r) {
                    if (gr + r < N_NODES)
                        xrf[(size_t)(gr + r) * 256 + c0 + wn + ni * 16 + l16] = acc[mi][ni][r] + bv;
                }
            }
        }
    }
}

// ---------------- fused GATv2 aggregation + column stats ----------------
// 1024 threads = 16 nodes per block; one wave per node; lane holds 4 channels.
// hB written as bf16; per-block column sums/sumsq accumulated into 64-slot stats.

__global__ __launch_bounds__(1024) void gat_agg(
    const u16* __restrict__ xlb, const float* __restrict__ xr,
    const int* __restrict__ rowptr, const int* __restrict__ col,
    const float* __restrict__ att_l, const float* __restrict__ bias_l,
    u16* __restrict__ hB, float* __restrict__ slot) {
    __shared__ float sred[16][520];
    int wid = threadIdx.x >> 6, lane = threadIdx.x & 63;
    int node = blockIdx.x * 16 + wid;   // 1250*16 == 20000 exactly
    const uint2* xl2 = (const uint2*)xlb;
    float4 attv = ((const float4*)att_l)[lane];
    float4 xrv = ((const float4*)xr)[(size_t)node * 64 + lane];
    int beg = rowptr[node], end = rowptr[node + 1];

    float denom = 0.f;
    float4 acc = make_float4(0.f, 0.f, 0.f, 0.f);

    int j = beg;
    for (; j + 8 <= end; j += 8) {
        int s[8];
        uint2 raw[8];
        float4 a[8];
        float p[8];
        #pragma unroll
        for (int u = 0; u < 8; ++u) s[u] = col[j + u];
        #pragma unroll
        for (int u = 0; u < 8; ++u) raw[u] = xl2[(size_t)s[u] * 64 + lane];
        #pragma unroll
        for (int u = 0; u < 8; ++u) {
            a[u] = bf2f4(raw[u]);
            float vx = a[u].x + xrv.x, vy = a[u].y + xrv.y;
            float vz = a[u].z + xrv.z, vw = a[u].w + xrv.w;
            vx = fmaxf(vx, 0.2f * vx);
            vy = fmaxf(vy, 0.2f * vy);
            vz = fmaxf(vz, 0.2f * vz);
            vw = fmaxf(vw, 0.2f * vw);
            p[u] = vx * attv.x + vy * attv.y + vz * attv.z + vw * attv.w;
        }
        #pragma unroll
        for (int u = 0; u < 8; ++u) p[u] = dpp_red16(p[u]);
        #pragma unroll
        for (int u = 0; u < 8; ++u) {
            float w = __expf(p[u]);
            denom += w;
            acc.x += w * a[u].x; acc.y += w * a[u].y;
            acc.z += w * a[u].z; acc.w += w * a[u].w;
        }
    }
    for (; j < end; ++j) {
        int s = col[j];
        float4 a = bf2f4(xl2[(size_t)s * 64 + lane]);
        float vx = a.x + xrv.x, vy = a.y + xrv.y;
        float vz = a.z + xrv.z, vw = a.w + xrv.w;
        vx = fmaxf(vx, 0.2f * vx);
        vy = fmaxf(vy, 0.2f * vy);
        vz = fmaxf(vz, 0.2f * vz);
        vw = fmaxf(vw, 0.2f * vw);
        float p = vx * attv.x + vy * attv.y + vz * attv.z + vw * attv.w;
        p = dpp_red16(p);
        float w = __expf(p);
        denom += w;
        acc.x += w * a.x; acc.y += w * a.y; acc.z += w * a.z; acc.w += w * a.w;
    }

    float inv = 1.f / denom;
    float4 b4 = ((const float4*)bias_l)[lane];
    float4 o;
    o.x = acc.x * inv + b4.x; o.y = acc.y * inv + b4.y;
    o.z = acc.z * inv + b4.z; o.w = acc.w * inv + b4.w;
    u16 ob[4] = {f2bf(o.x), f2bf(o.y), f2bf(o.z), f2bf(o.w)};
    ((uint2*)hB)[(size_t)node * 64 + lane] = *(const uint2*)ob;

    int cb2 = lane * 4;
    sred[wid][cb2 + 0] = o.x; sred[wid][cb2 + 1] = o.y;
    sred[wid][cb2 + 2] = o.z; sred[wid][cb2 + 3] = o.w;
    sred[wid][256 + cb2 + 0] = o.x * o.x; sred[wid][256 + cb2 + 1] = o.y * o.y;
    sred[wid][256 + cb2 + 2] = o.z * o.z; sred[wid][256 + cb2 + 3] = o.w * o.w;
    __syncthreads();
    int t = threadIdx.x;
    if (t < 512) {
        float s = 0.f;
        #pragma unroll
        for (int w = 0; w < 16; ++w) s += sred[w][t];
        atomicAdd(&slot[(blockIdx.x & (NSLOT - 1)) * 512 + t], s);
    }
}

// ---------------- pool with fused final GraphNorm+PReLU ----------------

__global__ __launch_bounds__(256) void pool_kernel(const u16* __restrict__ hB,
                                                   const int* __restrict__ batch,
                                                   const float* __restrict__ slots2,
                                                   const float* __restrict__ nw, const float* __restrict__ nb,
                                                   const float* __restrict__ na, const float* __restrict__ pa,
                                                   float* __restrict__ pooled) {
    __shared__ float accs[NBATCH][256];
    int c = threadIdx.x;
    float sum = 0.f, sq = 0.f;
    for (int s = 0; s < NSLOT; ++s) {
        sum += slots2[s * 512 + c];
        sq += slots2[s * 512 + 256 + c];
    }
    const float invn = 1.f / (float)N_NODES;
    float mean = sum * invn, Eh2 = sq * invn;
    float a = na[c];
    float var = Eh2 - (2.f * a - a * a) * mean * mean;
    float wc = nw[c] * rsqrtf(var + GEPS);
    float bb = nb[c] - a * mean * wc;
    float ap = pa[2];

    #pragma unroll
    for (int b = 0; b < NBATCH; ++b) accs[b][c] = 0.f;
    int r0 = blockIdx.x * 100;
    int r1 = min(N_NODES, r0 + 100);
    for (int i = r0; i < r1; ++i) {
        float v = __uint_as_float(((u32)hB[(size_t)i * 256 + c]) << 16);
        v = v * wc + bb;
        v = fmaxf(v, ap * v);
        accs[batch[i]][c] += v;
    }
    int bmin = batch[r0], bmax = batch[r1 - 1];
    for (int b = bmin; b <= bmax; ++b) atomicAdd(&pooled[b * 256 + c], accs[b][c]);
}

// ---------------- pooled GraphNorm + FC (single block) ----------------

__global__ __launch_bounds__(256) void poolnorm_fc(const float* __restrict__ pooled,
                                                   const float* __restrict__ nw, const float* __restrict__ nb,
                                                   const float* __restrict__ na,
                                                   const float* __restrict__ fcW, const float* __restrict__ fcb,
                                                   float* __restrict__ out) {
    __shared__ float pn[NBATCH][256];
    int c = threadIdx.x;
    float mean = 0.f, sq = 0.f;
    #pragma unroll
    for (int i = 0; i < NBATCH; ++i) {
        float v = pooled[i * 256 + c];
        mean += v; sq += v * v;
    }
    mean *= (1.f / NBATCH); sq *= (1.f / NBATCH);
    float a = na[c];
    float var = sq - (2.f * a - a * a) * mean * mean;
    float wc = nw[c] * rsqrtf(var + GEPS);
    float bb = nb[c] - a * mean * wc;
    #pragma unroll
    for (int i = 0; i < NBATCH; ++i)
        pn[i][c] = pooled[i * 256 + c] * wc + bb;
    __syncthreads();
    int o = c & 127, bset = c >> 7;
    for (int b = bset; b < NBATCH; b += 2) {
        float s = fcb[o];
        for (int k = 0; k < 256; ++k) s += pn[b][k] * fcW[k * 128 + o];
        out[b * 128 + o] = s;
    }
}

// ---------------- launch ----------------

extern "C" void kernel_launch(void* const* d_in, const int* in_sizes, int n_in,
                              void* d_out, int out_size, void* d_ws, size_t ws_size,
                              hipStream_t stream) {
    const float* x    = (const float*)d_in[0];
    const int*   ei   = (const int*)d_in[1];
    const int*   batch= (const int*)d_in[2];
    const float* Wl   = (const float*)d_in[3];
    const float* bl   = (const float*)d_in[4];
    const float* Wr   = (const float*)d_in[5];
    const float* br   = (const float*)d_in[6];
    const float* att  = (const float*)d_in[7];
    const float* cb   = (const float*)d_in[8];
    const float* pa   = (const float*)d_in[9];
    const float* nw   = (const float*)d_in[10];
    const float* nb   = (const float*)d_in[11];
    const float* na   = (const float*)d_in[12];
    const float* fcW  = (const float*)d_in[13];
    const float* fcb  = (const float*)d_in[14];
    float* out = (float*)d_out;

    char* ws = (char*)d_ws;
    size_t off = 0;
    auto carve = [&](size_t bytes) -> void* {
        void* p = (void*)(ws + off);
        off += (bytes + 255) & ~(size_t)255;
        return p;
    };
    // zero-span region (prep zeroes [rowptr, end-of-pooled))
    size_t z0 = off;
    int*   rowptr = (int*)carve((N_NODES + 1) * sizeof(int));
    int*   bar    = (int*)carve(16 * sizeof(int));
    float* slots  = (float*)carve((size_t)NLAYER * NSLOT * 512 * sizeof(float));
    float* pooled = (float*)carve(NBATCH * HC * sizeof(float));
    size_t z1 = off;
    // non-zeroed scratch
    int*   cursor = (int*)carve(N_NODES * sizeof(int));
    int*   blocksum = (int*)carve(256 * sizeof(int));
    int*   colidx = (int*)carve((size_t)ETOT * sizeof(int));
    u16*   xlb    = (u16*)carve((size_t)N_NODES * HC * sizeof(u16));
    float* xr     = (float*)carve((size_t)N_NODES * HC * sizeof(float));
    u16*   hB     = (u16*)carve((size_t)N_NODES * HC * sizeof(u16));
    u16*   xbf    = (u16*)carve((size_t)N_NODES * HC * sizeof(u16));
    u16*   WT     = (u16*)carve((size_t)NLAYER * 512 * 256 * sizeof(u16));

    int zq = (int)((z1 - z0) / 16);
    const int* srcp = ei;
    const int* dstp = ei + N_EDGES;

    prep<<<1504, 256, 0, stream>>>(x, xbf, Wl, Wr, WT, (uint4*)(ws + z0), zq);
    csr_fused<<<256, 256, 0, stream>>>(srcp, dstp, rowptr, cursor, colidx, bar, blocksum);

    for (int l = 0; l < NLAYER; ++l) {
        const u16* Asrc = (l == 0) ? xbf : hB;
        const float* slots_prev = slots + (size_t)((l > 0) ? (l - 1) : 0) * NSLOT * 512;
        gemm_mfma<<<dim3(157, 4), 256, 0, stream>>>(Asrc, slots_prev, nw, nb, na, pa,
                                                    (l > 0) ? (l - 1) : 0, (l > 0) ? 1 : 0,
                                                    WT + (size_t)l * 512 * 256,
                                                    bl + l * 256, br + l * 256, xlb, xr);
        gat_agg<<<1250, 1024, 0, stream>>>(xlb, xr, rowptr, colidx, att + l * 256, cb + l * 256,
                                           hB, slots + (size_t)l * NSLOT * 512);
    }
    pool_kernel<<<200, 256, 0, stream>>>(hB, batch, slots + (size_t)2 * NSLOT * 512,
                                         nw, nb, na, pa, pooled);
    poolnorm_fc<<<1, 256, 0, stream>>>(pooled, nw, nb, na, fcW, fcb, out);
}

// Round 6
// 533.772 us; speedup vs baseline: 1.1793x; 1.1793x over previous
//
#include <hip/hip_runtime.h>
#include <math.h>

#define N_NODES 20000
#define N_EDGES 640000
#define ETOT (N_EDGES + N_NODES)
#define HC 256
#define NLAYER 3
#define NBATCH 16
#define GEPS 1e-5f
#define NSLOT 64

typedef unsigned short u16;
typedef unsigned int u32;
typedef __attribute__((ext_vector_type(8))) short short8;
typedef __attribute__((ext_vector_type(4))) float floatx4;

__device__ __forceinline__ u16 f2bf(float f) {
    u32 u = __float_as_uint(f);
    u32 r = (u + 0x7FFFu + ((u >> 16) & 1u)) >> 16;
    return (u16)r;
}

__device__ __forceinline__ float4 bf2f4(uint2 u) {
    float4 r;
    r.x = __uint_as_float(u.x << 16);
    r.y = __uint_as_float(u.x & 0xFFFF0000u);
    r.z = __uint_as_float(u.y << 16);
    r.w = __uint_as_float(u.y & 0xFFFF0000u);
    return r;
}

// VALU-only 16-lane butterfly sum
__device__ __forceinline__ float dpp_red16(float x) {
    x += __int_as_float(__builtin_amdgcn_update_dpp(0, __float_as_int(x), 0xB1, 0xF, 0xF, true));
    x += __int_as_float(__builtin_amdgcn_update_dpp(0, __float_as_int(x), 0x4E, 0xF, 0xF, true));
    x += __int_as_float(__builtin_amdgcn_update_dpp(0, __float_as_int(x), 0x141, 0xF, 0xF, true));
    x += __int_as_float(__builtin_amdgcn_update_dpp(0, __float_as_int(x), 0x140, 0xF, 0xF, true));
    return x;
}

// ---------------- prep: convert x to bf16, transpose W, zero scratch ----------------
// grid: [0,1000) convert, [1000,1384) transpose, [1384,1504) zero

__global__ __launch_bounds__(256) void prep(const float* __restrict__ x, u16* __restrict__ xbf,
                                            const float* __restrict__ Wl, const float* __restrict__ Wr,
                                            u16* __restrict__ WT, uint4* __restrict__ zbase, int zq) {
    int b = blockIdx.x, tid = threadIdx.x;
    if (b < 1000) {
        for (int i = b * 256 + tid; i < 640000; i += 256000) {
            const float4* x4 = (const float4*)x + (size_t)i * 2;
            float4 a = x4[0], c = x4[1];
            u16 o[8] = {f2bf(a.x), f2bf(a.y), f2bf(a.z), f2bf(a.w),
                        f2bf(c.x), f2bf(c.y), f2bf(c.z), f2bf(c.w)};
            ((uint4*)xbf)[i] = *(const uint4*)o;
        }
    } else if (b < 1384) {
        __shared__ float T[32][33];
        int bi = b - 1000;
        int kb = bi & 7, nbk = (bi >> 3) & 15, l = bi >> 7;
        int n0 = nbk * 32, k0 = kb * 32;
        const float* W = ((n0 < 256) ? Wl : Wr) + (size_t)l * 65536;
        int nn = n0 & 255;
        int tx = tid & 31, ty = tid >> 5;
        #pragma unroll
        for (int i = 0; i < 4; ++i)
            T[ty + i * 8][tx] = W[(size_t)(k0 + ty + i * 8) * 256 + nn + tx];
        __syncthreads();
        u16* outw = WT + (size_t)l * 512 * 256;
        #pragma unroll
        for (int i = 0; i < 4; ++i)
            outw[(size_t)(n0 + ty + i * 8) * 256 + k0 + tx] = f2bf(T[tx][ty + i * 8]);
    } else {
        uint4 z = make_uint4(0, 0, 0, 0);
        for (int i = (b - 1384) * 256 + tid; i < zq; i += 120 * 256) zbase[i] = z;
    }
}

// ---------------- CSR build: count / scan / scatter ----------------

__global__ void count_deg(const int* __restrict__ dst, int* __restrict__ deg) {
    int e = blockIdx.x * 256 + threadIdx.x;
    if (e < N_EDGES) atomicAdd(&deg[dst[e]], 1);
}

// exclusive scan over (deg[i]+1) in-place -> rowptr, also fills cursor
__global__ __launch_bounds__(1024) void scan_excl(int* __restrict__ data, int* __restrict__ cursor) {
    __shared__ int wsum[16];
    __shared__ int carry_s;
    int tid = threadIdx.x, lane = tid & 63, wid = tid >> 6;
    if (tid == 0) carry_s = 0;
    __syncthreads();
    for (int base = 0; base < N_NODES; base += 1024) {
        int i = base + tid;
        int v = (i < N_NODES) ? (data[i] + 1) : 0;  // +1 = self-loop
        int x = v;
        #pragma unroll
        for (int off = 1; off < 64; off <<= 1) {
            int t = __shfl_up(x, off);
            if (lane >= off) x += t;
        }
        if (lane == 63) wsum[wid] = x;
        __syncthreads();
        int carry = carry_s;
        __syncthreads();
        if (tid == 0) {
            int run = 0;
            #pragma unroll
            for (int w2 = 0; w2 < 16; ++w2) { int t = wsum[w2]; wsum[w2] = run; run += t; }
            carry_s = carry + run;
        }
        __syncthreads();
        int excl = carry + wsum[wid] + x - v;
        if (i < N_NODES) { data[i] = excl; cursor[i] = excl; }
        __syncthreads();
    }
    if (tid == 0) data[N_NODES] = carry_s;
}

__global__ void scatter_edges(const int* __restrict__ src, const int* __restrict__ dst,
                              int* __restrict__ cursor, int* __restrict__ col) {
    int t = blockIdx.x * 256 + threadIdx.x;
    if (t < N_NODES) {
        int p = atomicAdd(&cursor[t], 1);
        col[p] = t;
    } else if (t < N_NODES + N_EDGES) {
        int e = t - N_NODES;
        int p = atomicAdd(&cursor[dst[e]], 1);
        col[p] = src[e];
    }
}

// ---------------- bf16 MFMA dual GEMM with fused GraphNorm+PReLU on A ----------------
// A: bf16 [20000][256] (xbf for layer 0, hB for layers 1-2); norm applied in staging.
// Outputs xl and xr both bf16.

__global__ __launch_bounds__(256) void gemm_mfma(
    const u16* __restrict__ Asrc, const float* __restrict__ slots_prev,
    const float* __restrict__ nw, const float* __restrict__ nb, const float* __restrict__ na,
    const float* __restrict__ pa, int prelu_idx, int use_norm,
    const u16* __restrict__ WT,
    const float* __restrict__ b0, const float* __restrict__ b1,
    u16* __restrict__ xlb, u16* __restrict__ xrb) {
    __shared__ u16 As[128][40];
    __shared__ u16 Bs[128][40];
    __shared__ float wcL[256], bbL[256];
    int row0 = blockIdx.x * 128;
    int nstrip = blockIdx.y;                 // 0,1 -> xl; 2,3 -> xr
    int ncol0 = nstrip * 128;
    const float* bias = (nstrip < 2) ? b0 : b1;
    u16* outp = (nstrip < 2) ? xlb : xrb;
    int c0 = (nstrip & 1) * 128;

    int tid = threadIdx.x;
    float ap = 0.f;
    if (use_norm) {
        int c = tid;
        float sum = 0.f, sq = 0.f;
        for (int s = 0; s < NSLOT; ++s) {
            sum += slots_prev[s * 512 + c];
            sq += slots_prev[s * 512 + 256 + c];
        }
        const float invn = 1.f / (float)N_NODES;
        float mean = sum * invn, Eh2 = sq * invn;
        float a = na[c];
        float var = Eh2 - (2.f * a - a * a) * mean * mean;
        float wc = nw[c] * rsqrtf(var + GEPS);
        wcL[c] = wc;
        bbL[c] = nb[c] - a * mean * wc;
        ap = pa[prelu_idx];
        __syncthreads();
    }

    int wave = tid >> 6, lane = tid & 63;
    int wm = (wave & 1) * 64, wn = (wave >> 1) * 64;
    int quad = lane >> 4, l16 = lane & 15;

    floatx4 acc[4][4] = {};

    int sr = tid >> 1;
    int sh = (tid & 1) * 16;

    for (int k0 = 0; k0 < 256; k0 += 32) {
        int gr = row0 + sr;
        uint4 av0 = make_uint4(0, 0, 0, 0), av1 = make_uint4(0, 0, 0, 0);
        if (gr < N_NODES) {
            const u16* p = Asrc + (size_t)gr * 256 + k0 + sh;
            av0 = *(const uint4*)p;
            av1 = *(const uint4*)(p + 8);
        }
        if (use_norm) {
            int kb2 = k0 + sh;
            u16 tmp[16];
            *(uint4*)tmp = av0;
            *(uint4*)(tmp + 8) = av1;
            u16 outv[16];
            #pragma unroll
            for (int j = 0; j < 16; ++j) {
                float vv = __uint_as_float(((u32)tmp[j]) << 16);
                float t2 = vv * wcL[kb2 + j] + bbL[kb2 + j];
                t2 = fmaxf(t2, ap * t2);
                outv[j] = f2bf(t2);
            }
            av0 = *(const uint4*)outv;
            av1 = *(const uint4*)(outv + 8);
        }
        const u16* q = WT + (size_t)(ncol0 + sr) * 256 + k0 + sh;
        uint4 bw0 = *(const uint4*)q;
        uint4 bw1 = *(const uint4*)(q + 8);
        *(uint4*)&As[sr][sh] = av0;
        *(uint4*)&As[sr][sh + 8] = av1;
        *(uint4*)&Bs[sr][sh] = bw0;
        *(uint4*)&Bs[sr][sh + 8] = bw1;
        __syncthreads();

        short8 af[4], bfr[4];
        #pragma unroll
        for (int mi = 0; mi < 4; ++mi)
            af[mi] = *(const short8*)&As[wm + mi * 16 + l16][quad * 8];
        #pragma unroll
        for (int ni = 0; ni < 4; ++ni)
            bfr[ni] = *(const short8*)&Bs[wn + ni * 16 + l16][quad * 8];
        #pragma unroll
        for (int mi = 0; mi < 4; ++mi)
            #pragma unroll
            for (int ni = 0; ni < 4; ++ni)
                acc[mi][ni] = __builtin_amdgcn_mfma_f32_16x16x32_bf16(af[mi], bfr[ni], acc[mi][ni], 0, 0, 0);
        __syncthreads();
    }

    // C/D layout: col = lane&15, row = quad*4 + reg
    #pragma unroll
    for (int ni = 0; ni < 4; ++ni) {
        int col = c0 + wn + ni * 16 + l16;
        float bv = bias[col];
        #pragma unroll
        for (int mi = 0; mi < 4; ++mi) {
            int gr = row0 + wm + mi * 16 + quad * 4;
            #pragma unroll
            for (int r = 0; r < 4; ++r) {
                if (gr + r < N_NODES)
                    outp[(size_t)(gr + r) * 256 + col] = f2bf(acc[mi][ni][r] + bv);
            }
        }
    }
}

// ---------------- fused GATv2 aggregation + column stats ----------------
// 1024 threads = 16 nodes per block; one wave per node; lane holds 4 channels.

__global__ __launch_bounds__(1024) void gat_agg(
    const u16* __restrict__ xlb, const u16* __restrict__ xrb,
    const int* __restrict__ rowptr, const int* __restrict__ col,
    const float* __restrict__ att_l, const float* __restrict__ bias_l,
    u16* __restrict__ hB, float* __restrict__ slot) {
    __shared__ float sred[16][520];
    int wid = threadIdx.x >> 6, lane = threadIdx.x & 63;
    int node = blockIdx.x * 16 + wid;   // 1250*16 == 20000 exactly
    const uint2* xl2 = (const uint2*)xlb;
    float4 attv = ((const float4*)att_l)[lane];
    float4 xrv = bf2f4(((const uint2*)xrb)[(size_t)node * 64 + lane]);
    int beg = rowptr[node], end = rowptr[node + 1];

    float denom = 0.f;
    float4 acc = make_float4(0.f, 0.f, 0.f, 0.f);

    int j = beg;
    for (; j + 8 <= end; j += 8) {
        int s[8];
        uint2 raw[8];
        float4 a[8];
        float p[8];
        #pragma unroll
        for (int u = 0; u < 8; ++u) s[u] = col[j + u];
        #pragma unroll
        for (int u = 0; u < 8; ++u) raw[u] = xl2[(size_t)s[u] * 64 + lane];
        #pragma unroll
        for (int u = 0; u < 8; ++u) {
            a[u] = bf2f4(raw[u]);
            float vx = a[u].x + xrv.x, vy = a[u].y + xrv.y;
            float vz = a[u].z + xrv.z, vw = a[u].w + xrv.w;
            vx = fmaxf(vx, 0.2f * vx);
            vy = fmaxf(vy, 0.2f * vy);
            vz = fmaxf(vz, 0.2f * vz);
            vw = fmaxf(vw, 0.2f * vw);
            p[u] = vx * attv.x + vy * attv.y + vz * attv.z + vw * attv.w;
        }
        #pragma unroll
        for (int u = 0; u < 8; ++u) p[u] = dpp_red16(p[u]);
        #pragma unroll
        for (int u = 0; u < 8; ++u) {
            float w = __expf(p[u]);
            denom += w;
            acc.x += w * a[u].x; acc.y += w * a[u].y;
            acc.z += w * a[u].z; acc.w += w * a[u].w;
        }
    }
    for (; j < end; ++j) {
        int s = col[j];
        float4 a = bf2f4(xl2[(size_t)s * 64 + lane]);
        float vx = a.x + xrv.x, vy = a.y + xrv.y;
        float vz = a.z + xrv.z, vw = a.w + xrv.w;
        vx = fmaxf(vx, 0.2f * vx);
        vy = fmaxf(vy, 0.2f * vy);
        vz = fmaxf(vz, 0.2f * vz);
        vw = fmaxf(vw, 0.2f * vw);
        float p = vx * attv.x + vy * attv.y + vz * attv.z + vw * attv.w;
        p = dpp_red16(p);
        float w = __expf(p);
        denom += w;
        acc.x += w * a.x; acc.y += w * a.y; acc.z += w * a.z; acc.w += w * a.w;
    }

    float inv = 1.f / denom;
    float4 b4 = ((const float4*)bias_l)[lane];
    float4 o;
    o.x = acc.x * inv + b4.x; o.y = acc.y * inv + b4.y;
    o.z = acc.z * inv + b4.z; o.w = acc.w * inv + b4.w;
    u16 ob[4] = {f2bf(o.x), f2bf(o.y), f2bf(o.z), f2bf(o.w)};
    ((uint2*)hB)[(size_t)node * 64 + lane] = *(const uint2*)ob;

    int cb2 = lane * 4;
    sred[wid][cb2 + 0] = o.x; sred[wid][cb2 + 1] = o.y;
    sred[wid][cb2 + 2] = o.z; sred[wid][cb2 + 3] = o.w;
    sred[wid][256 + cb2 + 0] = o.x * o.x; sred[wid][256 + cb2 + 1] = o.y * o.y;
    sred[wid][256 + cb2 + 2] = o.z * o.z; sred[wid][256 + cb2 + 3] = o.w * o.w;
    __syncthreads();
    int t = threadIdx.x;
    if (t < 512) {
        float s = 0.f;
        #pragma unroll
        for (int w = 0; w < 16; ++w) s += sred[w][t];
        atomicAdd(&slot[(blockIdx.x & (NSLOT - 1)) * 512 + t], s);
    }
}

// ---------------- pool with fused final GraphNorm+PReLU ----------------

__global__ __launch_bounds__(256) void pool_kernel(const u16* __restrict__ hB,
                                                   const int* __restrict__ batch,
                                                   const float* __restrict__ slots2,
                                                   const float* __restrict__ nw, const float* __restrict__ nb,
                                                   const float* __restrict__ na, const float* __restrict__ pa,
                                                   float* __restrict__ pooled) {
    __shared__ float accs[NBATCH][256];
    int c = threadIdx.x;
    float sum = 0.f, sq = 0.f;
    for (int s = 0; s < NSLOT; ++s) {
        sum += slots2[s * 512 + c];
        sq += slots2[s * 512 + 256 + c];
    }
    const float invn = 1.f / (float)N_NODES;
    float mean = sum * invn, Eh2 = sq * invn;
    float a = na[c];
    float var = Eh2 - (2.f * a - a * a) * mean * mean;
    float wc = nw[c] * rsqrtf(var + GEPS);
    float bb = nb[c] - a * mean * wc;
    float ap = pa[2];

    #pragma unroll
    for (int b = 0; b < NBATCH; ++b) accs[b][c] = 0.f;
    int r0 = blockIdx.x * 100;
    int r1 = min(N_NODES, r0 + 100);
    for (int i = r0; i < r1; ++i) {
        float v = __uint_as_float(((u32)hB[(size_t)i * 256 + c]) << 16);
        v = v * wc + bb;
        v = fmaxf(v, ap * v);
        accs[batch[i]][c] += v;
    }
    int bmin = batch[r0], bmax = batch[r1 - 1];
    for (int b = bmin; b <= bmax; ++b) atomicAdd(&pooled[b * 256 + c], accs[b][c]);
}

// ---------------- pooled GraphNorm + FC (single block) ----------------

__global__ __launch_bounds__(256) void poolnorm_fc(const float* __restrict__ pooled,
                                                   const float* __restrict__ nw, const float* __restrict__ nb,
                                                   const float* __restrict__ na,
                                                   const float* __restrict__ fcW, const float* __restrict__ fcb,
                                                   float* __restrict__ out) {
    __shared__ float pn[NBATCH][256];
    int c = threadIdx.x;
    float mean = 0.f, sq = 0.f;
    #pragma unroll
    for (int i = 0; i < NBATCH; ++i) {
        float v = pooled[i * 256 + c];
        mean += v; sq += v * v;
    }
    mean *= (1.f / NBATCH); sq *= (1.f / NBATCH);
    float a = na[c];
    float var = sq - (2.f * a - a * a) * mean * mean;
    float wc = nw[c] * rsqrtf(var + GEPS);
    float bb = nb[c] - a * mean * wc;
    #pragma unroll
    for (int i = 0; i < NBATCH; ++i)
        pn[i][c] = pooled[i * 256 + c] * wc + bb;
    __syncthreads();
    int o = c & 127, bset = c >> 7;
    for (int b = bset; b < NBATCH; b += 2) {
        float s = fcb[o];
        for (int k = 0; k < 256; ++k) s += pn[b][k] * fcW[k * 128 + o];
        out[b * 128 + o] = s;
    }
}

// ---------------- launch ----------------

extern "C" void kernel_launch(void* const* d_in, const int* in_sizes, int n_in,
                              void* d_out, int out_size, void* d_ws, size_t ws_size,
                              hipStream_t stream) {
    const float* x    = (const float*)d_in[0];
    const int*   ei   = (const int*)d_in[1];
    const int*   batch= (const int*)d_in[2];
    const float* Wl   = (const float*)d_in[3];
    const float* bl   = (const float*)d_in[4];
    const float* Wr   = (const float*)d_in[5];
    const float* br   = (const float*)d_in[6];
    const float* att  = (const float*)d_in[7];
    const float* cb   = (const float*)d_in[8];
    const float* pa   = (const float*)d_in[9];
    const float* nw   = (const float*)d_in[10];
    const float* nb   = (const float*)d_in[11];
    const float* na   = (const float*)d_in[12];
    const float* fcW  = (const float*)d_in[13];
    const float* fcb  = (const float*)d_in[14];
    float* out = (float*)d_out;

    char* ws = (char*)d_ws;
    size_t off = 0;
    auto carve = [&](size_t bytes) -> void* {
        void* p = (void*)(ws + off);
        off += (bytes + 255) & ~(size_t)255;
        return p;
    };
    // zero-span region (prep zeroes [rowptr, end-of-pooled))
    size_t z0 = off;
    int*   rowptr = (int*)carve((N_NODES + 1) * sizeof(int));
    float* slots  = (float*)carve((size_t)NLAYER * NSLOT * 512 * sizeof(float));
    float* pooled = (float*)carve(NBATCH * HC * sizeof(float));
    size_t z1 = off;
    // non-zeroed scratch
    int*   cursor = (int*)carve(N_NODES * sizeof(int));
    int*   colidx = (int*)carve((size_t)ETOT * sizeof(int));
    u16*   xlb    = (u16*)carve((size_t)N_NODES * HC * sizeof(u16));
    u16*   xrb    = (u16*)carve((size_t)N_NODES * HC * sizeof(u16));
    u16*   hB     = (u16*)carve((size_t)N_NODES * HC * sizeof(u16));
    u16*   xbf    = (u16*)carve((size_t)N_NODES * HC * sizeof(u16));
    u16*   WT     = (u16*)carve((size_t)NLAYER * 512 * 256 * sizeof(u16));

    int zq = (int)((z1 - z0) / 16);
    const int* srcp = ei;
    const int* dstp = ei + N_EDGES;

    prep<<<1504, 256, 0, stream>>>(x, xbf, Wl, Wr, WT, (uint4*)(ws + z0), zq);
    count_deg<<<(N_EDGES + 255) / 256, 256, 0, stream>>>(dstp, rowptr);
    scan_excl<<<1, 1024, 0, stream>>>(rowptr, cursor);
    scatter_edges<<<(ETOT + 255) / 256, 256, 0, stream>>>(srcp, dstp, cursor, colidx);

    for (int l = 0; l < NLAYER; ++l) {
        const u16* Asrc = (l == 0) ? xbf : hB;
        const float* slots_prev = slots + (size_t)((l > 0) ? (l - 1) : 0) * NSLOT * 512;
        gemm_mfma<<<dim3(157, 4), 256, 0, stream>>>(Asrc, slots_prev, nw, nb, na, pa,
                                                    (l > 0) ? (l - 1) : 0, (l > 0) ? 1 : 0,
                                                    WT + (size_t)l * 512 * 256,
                                                    bl + l * 256, br + l * 256, xlb, xrb);
        gat_agg<<<1250, 1024, 0, stream>>>(xlb, xrb, rowptr, colidx, att + l * 256, cb + l * 256,
                                           hB, slots + (size_t)l * NSLOT * 512);
    }
    pool_kernel<<<200, 256, 0, stream>>>(hB, batch, slots + (size_t)2 * NSLOT * 512,
                                         nw, nb, na, pa, pooled);
    poolnorm_fc<<<1, 256, 0, stream>>>(pooled, nw, nb, na, fcW, fcb, out);
}

// Round 7
// 488.528 us; speedup vs baseline: 1.2885x; 1.0926x over previous
//
#include <hip/hip_runtime.h>
#include <math.h>

#define N_NODES 20000
#define N_EDGES 640000
#define ETOT (N_EDGES + N_NODES)
#define HC 256
#define NLAYER 3
#define NBATCH 16
#define GEPS 1e-5f
#define NSLOT 64

typedef unsigned short u16;
typedef unsigned int u32;
typedef __attribute__((ext_vector_type(8))) short short8;
typedef __attribute__((ext_vector_type(4))) float floatx4;

__device__ __forceinline__ u16 f2bf(float f) {
    u32 u = __float_as_uint(f);
    u32 r = (u + 0x7FFFu + ((u >> 16) & 1u)) >> 16;
    return (u16)r;
}

__device__ __forceinline__ float4 bf2f4(uint2 u) {
    float4 r;
    r.x = __uint_as_float(u.x << 16);
    r.y = __uint_as_float(u.x & 0xFFFF0000u);
    r.z = __uint_as_float(u.y << 16);
    r.w = __uint_as_float(u.y & 0xFFFF0000u);
    return r;
}

// VALU-only 16-lane butterfly sum
__device__ __forceinline__ float dpp_red16(float x) {
    x += __int_as_float(__builtin_amdgcn_update_dpp(0, __float_as_int(x), 0xB1, 0xF, 0xF, true));
    x += __int_as_float(__builtin_amdgcn_update_dpp(0, __float_as_int(x), 0x4E, 0xF, 0xF, true));
    x += __int_as_float(__builtin_amdgcn_update_dpp(0, __float_as_int(x), 0x141, 0xF, 0xF, true));
    x += __int_as_float(__builtin_amdgcn_update_dpp(0, __float_as_int(x), 0x140, 0xF, 0xF, true));
    return x;
}

// ---------------- prep: convert x to bf16, transpose W, zero scratch ----------------
// grid: [0,1000) convert, [1000,1384) transpose, [1384,1504) zero

__global__ __launch_bounds__(256) void prep(const float* __restrict__ x, u16* __restrict__ xbf,
                                            const float* __restrict__ Wl, const float* __restrict__ Wr,
                                            u16* __restrict__ WT, uint4* __restrict__ zbase, int zq) {
    int b = blockIdx.x, tid = threadIdx.x;
    if (b < 1000) {
        for (int i = b * 256 + tid; i < 640000; i += 256000) {
            const float4* x4 = (const float4*)x + (size_t)i * 2;
            float4 a = x4[0], c = x4[1];
            u16 o[8] = {f2bf(a.x), f2bf(a.y), f2bf(a.z), f2bf(a.w),
                        f2bf(c.x), f2bf(c.y), f2bf(c.z), f2bf(c.w)};
            ((uint4*)xbf)[i] = *(const uint4*)o;
        }
    } else if (b < 1384) {
        __shared__ float T[32][33];
        int bi = b - 1000;
        int kb = bi & 7, nbk = (bi >> 3) & 15, l = bi >> 7;
        int n0 = nbk * 32, k0 = kb * 32;
        const float* W = ((n0 < 256) ? Wl : Wr) + (size_t)l * 65536;
        int nn = n0 & 255;
        int tx = tid & 31, ty = tid >> 5;
        #pragma unroll
        for (int i = 0; i < 4; ++i)
            T[ty + i * 8][tx] = W[(size_t)(k0 + ty + i * 8) * 256 + nn + tx];
        __syncthreads();
        u16* outw = WT + (size_t)l * 512 * 256;
        #pragma unroll
        for (int i = 0; i < 4; ++i)
            outw[(size_t)(n0 + ty + i * 8) * 256 + k0 + tx] = f2bf(T[tx][ty + i * 8]);
    } else {
        uint4 z = make_uint4(0, 0, 0, 0);
        for (int i = (b - 1384) * 256 + tid; i < zq; i += 120 * 256) zbase[i] = z;
    }
}

// ---------------- CSR build: count / scan / scatter ----------------

__global__ void count_deg(const int* __restrict__ dst, int* __restrict__ deg) {
    int e = blockIdx.x * 256 + threadIdx.x;
    if (e < N_EDGES) atomicAdd(&deg[dst[e]], 1);
}

// single-pass scan: each thread owns 20 rows; exclusive scan of (deg+1) -> rowptr/cursor
__global__ __launch_bounds__(1024) void scan_excl(int* __restrict__ data, int* __restrict__ cursor) {
    __shared__ int wsum[16];
    int t = threadIdx.x, lane = t & 63, wid = t >> 6;
    int i0 = t * 20;
    int d[20];
    int tot = 0;
    #pragma unroll
    for (int j = 0; j < 20; ++j) {
        int i = i0 + j;
        int v = (i < N_NODES) ? (data[i] + 1) : 0;  // +1 = self-loop
        d[j] = v;
        tot += v;
    }
    int x = tot;
    #pragma unroll
    for (int off = 1; off < 64; off <<= 1) {
        int tmp = __shfl_up(x, off);
        if (lane >= off) x += tmp;
    }
    if (lane == 63) wsum[wid] = x;
    __syncthreads();
    if (t == 0) {
        int run = 0;
        #pragma unroll
        for (int w = 0; w < 16; ++w) { int tv = wsum[w]; wsum[w] = run; run += tv; }
    }
    __syncthreads();
    int run = wsum[wid] + x - tot;  // exclusive prefix for this thread
    #pragma unroll
    for (int j = 0; j < 20; ++j) {
        int i = i0 + j;
        if (i < N_NODES) { data[i] = run; cursor[i] = run; }
        run += d[j];
    }
    if (t == 0) data[N_NODES] = ETOT;
}

__global__ void scatter_edges(const int* __restrict__ src, const int* __restrict__ dst,
                              int* __restrict__ cursor, int* __restrict__ col) {
    int t = blockIdx.x * 256 + threadIdx.x;
    if (t < N_NODES) {
        int p = atomicAdd(&cursor[t], 1);
        col[p] = t;
    } else if (t < N_NODES + N_EDGES) {
        int e = t - N_NODES;
        int p = atomicAdd(&cursor[dst[e]], 1);
        col[p] = src[e];
    }
}

// ---------------- bf16 MFMA dual GEMM with fused GraphNorm+PReLU on A ----------------

__global__ __launch_bounds__(256) void gemm_mfma(
    const u16* __restrict__ Asrc, const float* __restrict__ slots_prev,
    const float* __restrict__ nw, const float* __restrict__ nb, const float* __restrict__ na,
    const float* __restrict__ pa, int prelu_idx, int use_norm,
    const u16* __restrict__ WT,
    const float* __restrict__ b0, const float* __restrict__ b1,
    u16* __restrict__ xlb, u16* __restrict__ xrb) {
    __shared__ u16 As[128][40];
    __shared__ u16 Bs[128][40];
    __shared__ float wcL[256], bbL[256];
    int row0 = blockIdx.x * 128;
    int nstrip = blockIdx.y;                 // 0,1 -> xl; 2,3 -> xr
    int ncol0 = nstrip * 128;
    const float* bias = (nstrip < 2) ? b0 : b1;
    u16* outp = (nstrip < 2) ? xlb : xrb;
    int c0 = (nstrip & 1) * 128;

    int tid = threadIdx.x;
    float ap = 0.f;
    if (use_norm) {
        int c = tid;
        float sum = 0.f, sq = 0.f;
        for (int s = 0; s < NSLOT; ++s) {
            sum += slots_prev[s * 512 + c];
            sq += slots_prev[s * 512 + 256 + c];
        }
        const float invn = 1.f / (float)N_NODES;
        float mean = sum * invn, Eh2 = sq * invn;
        float a = na[c];
        float var = Eh2 - (2.f * a - a * a) * mean * mean;
        float wc = nw[c] * rsqrtf(var + GEPS);
        wcL[c] = wc;
        bbL[c] = nb[c] - a * mean * wc;
        ap = pa[prelu_idx];
        __syncthreads();
    }

    int wave = tid >> 6, lane = tid & 63;
    int wm = (wave & 1) * 64, wn = (wave >> 1) * 64;
    int quad = lane >> 4, l16 = lane & 15;

    floatx4 acc[4][4] = {};

    int sr = tid >> 1;
    int sh = (tid & 1) * 16;

    for (int k0 = 0; k0 < 256; k0 += 32) {
        int gr = row0 + sr;
        uint4 av0 = make_uint4(0, 0, 0, 0), av1 = make_uint4(0, 0, 0, 0);
        if (gr < N_NODES) {
            const u16* p = Asrc + (size_t)gr * 256 + k0 + sh;
            av0 = *(const uint4*)p;
            av1 = *(const uint4*)(p + 8);
        }
        if (use_norm) {
            int kb2 = k0 + sh;
            u16 tmp[16];
            *(uint4*)tmp = av0;
            *(uint4*)(tmp + 8) = av1;
            float4 wv0 = *(const float4*)&wcL[kb2], wv1 = *(const float4*)&wcL[kb2 + 4];
            float4 wv2 = *(const float4*)&wcL[kb2 + 8], wv3 = *(const float4*)&wcL[kb2 + 12];
            float4 bv0 = *(const float4*)&bbL[kb2], bv1 = *(const float4*)&bbL[kb2 + 4];
            float4 bv2 = *(const float4*)&bbL[kb2 + 8], bv3 = *(const float4*)&bbL[kb2 + 12];
            float wvf[16] = {wv0.x, wv0.y, wv0.z, wv0.w, wv1.x, wv1.y, wv1.z, wv1.w,
                             wv2.x, wv2.y, wv2.z, wv2.w, wv3.x, wv3.y, wv3.z, wv3.w};
            float bvf[16] = {bv0.x, bv0.y, bv0.z, bv0.w, bv1.x, bv1.y, bv1.z, bv1.w,
                             bv2.x, bv2.y, bv2.z, bv2.w, bv3.x, bv3.y, bv3.z, bv3.w};
            u16 outv[16];
            #pragma unroll
            for (int j = 0; j < 16; ++j) {
                float vv = __uint_as_float(((u32)tmp[j]) << 16);
                float t2 = vv * wvf[j] + bvf[j];
                t2 = fmaxf(t2, ap * t2);
                outv[j] = f2bf(t2);
            }
            av0 = *(const uint4*)outv;
            av1 = *(const uint4*)(outv + 8);
        }
        const u16* q = WT + (size_t)(ncol0 + sr) * 256 + k0 + sh;
        uint4 bw0 = *(const uint4*)q;
        uint4 bw1 = *(const uint4*)(q + 8);
        *(uint4*)&As[sr][sh] = av0;
        *(uint4*)&As[sr][sh + 8] = av1;
        *(uint4*)&Bs[sr][sh] = bw0;
        *(uint4*)&Bs[sr][sh + 8] = bw1;
        __syncthreads();

        short8 af[4], bfr[4];
        #pragma unroll
        for (int mi = 0; mi < 4; ++mi)
            af[mi] = *(const short8*)&As[wm + mi * 16 + l16][quad * 8];
        #pragma unroll
        for (int ni = 0; ni < 4; ++ni)
            bfr[ni] = *(const short8*)&Bs[wn + ni * 16 + l16][quad * 8];
        #pragma unroll
        for (int mi = 0; mi < 4; ++mi)
            #pragma unroll
            for (int ni = 0; ni < 4; ++ni)
                acc[mi][ni] = __builtin_amdgcn_mfma_f32_16x16x32_bf16(af[mi], bfr[ni], acc[mi][ni], 0, 0, 0);
        __syncthreads();
    }

    // C/D layout: col = lane&15, row = quad*4 + reg
    #pragma unroll
    for (int ni = 0; ni < 4; ++ni) {
        int col = c0 + wn + ni * 16 + l16;
        float bv = bias[col];
        #pragma unroll
        for (int mi = 0; mi < 4; ++mi) {
            int gr = row0 + wm + mi * 16 + quad * 4;
            #pragma unroll
            for (int r = 0; r < 4; ++r) {
                if (gr + r < N_NODES)
                    outp[(size_t)(gr + r) * 256 + col] = f2bf(acc[mi][ni][r] + bv);
            }
        }
    }
}

// ---------------- fused GATv2 aggregation + column stats ----------------
// 256 threads = 4 nodes per block; one wave per node; lane holds 4 channels.

__global__ __launch_bounds__(256) void gat_agg(
    const u16* __restrict__ xlb, const u16* __restrict__ xrb,
    const int* __restrict__ rowptr, const int* __restrict__ col,
    const float* __restrict__ att_l, const float* __restrict__ bias_l,
    u16* __restrict__ hB, float* __restrict__ slot) {
    __shared__ float sred[4][520];
    int wid = threadIdx.x >> 6, lane = threadIdx.x & 63;
    int node = blockIdx.x * 4 + wid;   // 5000*4 == 20000 exactly
    const uint2* xl2 = (const uint2*)xlb;
    float4 attv = ((const float4*)att_l)[lane];
    float4 xrv = bf2f4(((const uint2*)xrb)[(size_t)node * 64 + lane]);
    int beg = rowptr[node], end = rowptr[node + 1];

    float denom = 0.f;
    float4 acc = make_float4(0.f, 0.f, 0.f, 0.f);

    int j = beg;
    for (; j + 8 <= end; j += 8) {
        int s[8];
        uint2 raw[8];
        float4 a[8];
        float p[8];
        #pragma unroll
        for (int u = 0; u < 8; ++u) s[u] = col[j + u];
        #pragma unroll
        for (int u = 0; u < 8; ++u) raw[u] = xl2[(size_t)s[u] * 64 + lane];
        #pragma unroll
        for (int u = 0; u < 8; ++u) {
            a[u] = bf2f4(raw[u]);
            float vx = a[u].x + xrv.x, vy = a[u].y + xrv.y;
            float vz = a[u].z + xrv.z, vw = a[u].w + xrv.w;
            vx = fmaxf(vx, 0.2f * vx);
            vy = fmaxf(vy, 0.2f * vy);
            vz = fmaxf(vz, 0.2f * vz);
            vw = fmaxf(vw, 0.2f * vw);
            p[u] = vx * attv.x + vy * attv.y + vz * attv.z + vw * attv.w;
        }
        #pragma unroll
        for (int u = 0; u < 8; ++u) p[u] = dpp_red16(p[u]);
        #pragma unroll
        for (int u = 0; u < 8; ++u) {
            float w = __expf(p[u]);
            denom += w;
            acc.x += w * a[u].x; acc.y += w * a[u].y;
            acc.z += w * a[u].z; acc.w += w * a[u].w;
        }
    }
    for (; j < end; ++j) {
        int s = col[j];
        float4 a = bf2f4(xl2[(size_t)s * 64 + lane]);
        float vx = a.x + xrv.x, vy = a.y + xrv.y;
        float vz = a.z + xrv.z, vw = a.w + xrv.w;
        vx = fmaxf(vx, 0.2f * vx);
        vy = fmaxf(vy, 0.2f * vy);
        vz = fmaxf(vz, 0.2f * vz);
        vw = fmaxf(vw, 0.2f * vw);
        float p = vx * attv.x + vy * attv.y + vz * attv.z + vw * attv.w;
        p = dpp_red16(p);
        float w = __expf(p);
        denom += w;
        acc.x += w * a.x; acc.y += w * a.y; acc.z += w * a.z; acc.w += w * a.w;
    }

    float inv = 1.f / denom;
    float4 b4 = ((const float4*)bias_l)[lane];
    float4 o;
    o.x = acc.x * inv + b4.x; o.y = acc.y * inv + b4.y;
    o.z = acc.z * inv + b4.z; o.w = acc.w * inv + b4.w;
    u16 ob[4] = {f2bf(o.x), f2bf(o.y), f2bf(o.z), f2bf(o.w)};
    ((uint2*)hB)[(size_t)node * 64 + lane] = *(const uint2*)ob;

    int cb2 = lane * 4;
    sred[wid][cb2 + 0] = o.x; sred[wid][cb2 + 1] = o.y;
    sred[wid][cb2 + 2] = o.z; sred[wid][cb2 + 3] = o.w;
    sred[wid][256 + cb2 + 0] = o.x * o.x; sred[wid][256 + cb2 + 1] = o.y * o.y;
    sred[wid][256 + cb2 + 2] = o.z * o.z; sred[wid][256 + cb2 + 3] = o.w * o.w;
    __syncthreads();
    int t = threadIdx.x;
    #pragma unroll
    for (int h = 0; h < 2; ++h) {
        int idx = t + h * 256;
        float s = sred[0][idx] + sred[1][idx] + sred[2][idx] + sred[3][idx];
        atomicAdd(&slot[(blockIdx.x & (NSLOT - 1)) * 512 + idx], s);
    }
}

// ---------------- pool with fused final GraphNorm+PReLU ----------------

__global__ __launch_bounds__(256) void pool_kernel(const u16* __restrict__ hB,
                                                   const int* __restrict__ batch,
                                                   const float* __restrict__ slots2,
                                                   const float* __restrict__ nw, const float* __restrict__ nb,
                                                   const float* __restrict__ na, const float* __restrict__ pa,
                                                   float* __restrict__ pooled) {
    __shared__ float accs[NBATCH][256];
    int c = threadIdx.x;
    float sum = 0.f, sq = 0.f;
    for (int s = 0; s < NSLOT; ++s) {
        sum += slots2[s * 512 + c];
        sq += slots2[s * 512 + 256 + c];
    }
    const float invn = 1.f / (float)N_NODES;
    float mean = sum * invn, Eh2 = sq * invn;
    float a = na[c];
    float var = Eh2 - (2.f * a - a * a) * mean * mean;
    float wc = nw[c] * rsqrtf(var + GEPS);
    float bb = nb[c] - a * mean * wc;
    float ap = pa[2];

    #pragma unroll
    for (int b = 0; b < NBATCH; ++b) accs[b][c] = 0.f;
    int r0 = blockIdx.x * 100;
    int r1 = min(N_NODES, r0 + 100);
    for (int i = r0; i < r1; ++i) {
        float v = __uint_as_float(((u32)hB[(size_t)i * 256 + c]) << 16);
        v = v * wc + bb;
        v = fmaxf(v, ap * v);
        accs[batch[i]][c] += v;
    }
    int bmin = batch[r0], bmax = batch[r1 - 1];
    for (int b = bmin; b <= bmax; ++b) atomicAdd(&pooled[b * 256 + c], accs[b][c]);
}

// ---------------- pooled GraphNorm (1 block) ----------------

__global__ __launch_bounds__(256) void pool_norm(const float* __restrict__ pooled,
                                                 const float* __restrict__ nw, const float* __restrict__ nb,
                                                 const float* __restrict__ na,
                                                 float* __restrict__ pn) {
    int c = threadIdx.x;
    float mean = 0.f, sq = 0.f;
    #pragma unroll
    for (int i = 0; i < NBATCH; ++i) {
        float v = pooled[i * 256 + c];
        mean += v; sq += v * v;
    }
    mean *= (1.f / NBATCH); sq *= (1.f / NBATCH);
    float a = na[c];
    float var = sq - (2.f * a - a * a) * mean * mean;
    float wc = nw[c] * rsqrtf(var + GEPS);
    float bb = nb[c] - a * mean * wc;
    #pragma unroll
    for (int i = 0; i < NBATCH; ++i)
        pn[i * 256 + c] = pooled[i * 256 + c] * wc + bb;
}

// ---------------- FC: 16 blocks, k split in halves + LDS reduce ----------------

__global__ __launch_bounds__(256) void fc_kernel(const float* __restrict__ pn,
                                                 const float* __restrict__ fcW, const float* __restrict__ fcb,
                                                 float* __restrict__ out) {
    __shared__ float pnl[256];
    __shared__ float part[128];
    int b = blockIdx.x;
    int t = threadIdx.x;
    pnl[t] = pn[b * 256 + t];
    __syncthreads();
    int o = t & 127, half = t >> 7;
    float s = 0.f;
    int kbase = half * 128;
    #pragma unroll 8
    for (int k = 0; k < 128; ++k)
        s += pnl[kbase + k] * fcW[(kbase + k) * 128 + o];
    if (half == 1) part[o] = s;
    __syncthreads();
    if (half == 0) out[b * 128 + o] = s + part[o] + fcb[o];
}

// ---------------- launch ----------------

extern "C" void kernel_launch(void* const* d_in, const int* in_sizes, int n_in,
                              void* d_out, int out_size, void* d_ws, size_t ws_size,
                              hipStream_t stream) {
    const float* x    = (const float*)d_in[0];
    const int*   ei   = (const int*)d_in[1];
    const int*   batch= (const int*)d_in[2];
    const float* Wl   = (const float*)d_in[3];
    const float* bl   = (const float*)d_in[4];
    const float* Wr   = (const float*)d_in[5];
    const float* br   = (const float*)d_in[6];
    const float* att  = (const float*)d_in[7];
    const float* cb   = (const float*)d_in[8];
    const float* pa   = (const float*)d_in[9];
    const float* nw   = (const float*)d_in[10];
    const float* nb   = (const float*)d_in[11];
    const float* na   = (const float*)d_in[12];
    const float* fcW  = (const float*)d_in[13];
    const float* fcb  = (const float*)d_in[14];
    float* out = (float*)d_out;

    char* ws = (char*)d_ws;
    size_t off = 0;
    auto carve = [&](size_t bytes) -> void* {
        void* p = (void*)(ws + off);
        off += (bytes + 255) & ~(size_t)255;
        return p;
    };
    // zero-span region (prep zeroes [rowptr, end-of-pooled))
    size_t z0 = off;
    int*   rowptr = (int*)carve((N_NODES + 1) * sizeof(int));
    float* slots  = (float*)carve((size_t)NLAYER * NSLOT * 512 * sizeof(float));
    float* pooled = (float*)carve(NBATCH * HC * sizeof(float));
    size_t z1 = off;
    // non-zeroed scratch
    int*   cursor = (int*)carve(N_NODES * sizeof(int));
    int*   colidx = (int*)carve((size_t)ETOT * sizeof(int));
    u16*   xlb    = (u16*)carve((size_t)N_NODES * HC * sizeof(u16));
    u16*   xrb    = (u16*)carve((size_t)N_NODES * HC * sizeof(u16));
    u16*   hB     = (u16*)carve((size_t)N_NODES * HC * sizeof(u16));
    u16*   xbf    = (u16*)carve((size_t)N_NODES * HC * sizeof(u16));
    u16*   WT     = (u16*)carve((size_t)NLAYER * 512 * 256 * sizeof(u16));
    float* pn     = (float*)carve(NBATCH * HC * sizeof(float));

    int zq = (int)((z1 - z0) / 16);
    const int* srcp = ei;
    const int* dstp = ei + N_EDGES;

    prep<<<1504, 256, 0, stream>>>(x, xbf, Wl, Wr, WT, (uint4*)(ws + z0), zq);
    count_deg<<<(N_EDGES + 255) / 256, 256, 0, stream>>>(dstp, rowptr);
    scan_excl<<<1, 1024, 0, stream>>>(rowptr, cursor);
    scatter_edges<<<(ETOT + 255) / 256, 256, 0, stream>>>(srcp, dstp, cursor, colidx);

    for (int l = 0; l < NLAYER; ++l) {
        const u16* Asrc = (l == 0) ? xbf : hB;
        const float* slots_prev = slots + (size_t)((l > 0) ? (l - 1) : 0) * NSLOT * 512;
        gemm_mfma<<<dim3(157, 4), 256, 0, stream>>>(Asrc, slots_prev, nw, nb, na, pa,
                                                    (l > 0) ? (l - 1) : 0, (l > 0) ? 1 : 0,
                                                    WT + (size_t)l * 512 * 256,
                                                    bl + l * 256, br + l * 256, xlb, xrb);
        gat_agg<<<5000, 256, 0, stream>>>(xlb, xrb, rowptr, colidx, att + l * 256, cb + l * 256,
                                          hB, slots + (size_t)l * NSLOT * 512);
    }
    pool_kernel<<<200, 256, 0, stream>>>(hB, batch, slots + (size_t)2 * NSLOT * 512,
                                         nw, nb, na, pa, pooled);
    pool_norm<<<1, 256, 0, stream>>>(pooled, nw, nb, na, pn);
    fc_kernel<<<NBATCH, 256, 0, stream>>>(pn, fcW, fcb, out);
}